// Round 8
// baseline (275.590 us; speedup 1.0000x reference)
//
#include <hip/hip_runtime.h>
#include <math.h>

#define HH 384
#define WW 384
#define NIMG 272
#define IMG_STRIDE (HH * WW)
#define TDW 128                          // tile width
#define TDH 16                           // tile height (output rows)
#define XT (WW / TDW)                    // 3
#define YT (HH / TDH)                    // 24
#define NBLOCKS (NIMG * XT * YT)         // 19584, % 8 == 0
#define NXCD 8
#define LROWS (TDH + 2)                  // 18 LDS rows (y0-1 .. y0+16)
#define NDMA 9                           // 9 instr * 64 lanes * 16B = 18*128*4 B

typedef float f4_t __attribute__((ext_vector_type(4)));

__device__ __forceinline__ float max3f(float a, float b, float c) {
    return fmaxf(fmaxf(a, b), c);        // -> v_max3_f32
}
__device__ __forceinline__ float fast_sigmoid(float v) {
    return __fdividef(1.0f, 1.0f + __expf(-v));
}

// Round-8: wave-autonomous DMA tiles. r5-7 showed DMA staging alone doesn't
// beat register staging (~90us tie across ALL barrier-coupled structures);
// r1/r3 counters (HBM 29%, VALU 23%, occ 50%) say nothing saturates. The
// remaining shared cost: every structure couples 4+ waves behind a full
// vmcnt(0)+s_barrier drain, 38 block-rounds deep. This kernel has ZERO
// barriers: one wave (64-thr block) owns a 128x16 tile, issues 9
// global_load_lds dwordx4 (18 rows x 128 cols, no x-halo in DMA -> no
// clamp fixups at all), waits on ITS OWN vmcnt(0), computes. 16 autonomous
// waves/CU (LDS-capped), each with 9 KB of DMA in flight -> fill-like
// independence, which is what the 6.7 TB/s fills have and no prior round had.
// Horizontal halo: interior cols via __shfl from the neighbor lane's b128;
// tile-edge cols via 10 scalar loads on lanes f4c==0/31 (L2-hot).
__global__ __launch_bounds__(64) void
heatmap_peaks_wave(const float* __restrict__ in, float* __restrict__ out) {
    __shared__ float S[LROWS * TDW];     // 9216 B
    const float NEG = -INFINITY;
    const f4_t NEG4 = {NEG, NEG, NEG, NEG};

    int lane = (int)threadIdx.x;         // one wave per block
    int bid  = (int)blockIdx.x;
    int swz  = (bid % NXCD) * (NBLOCKS / NXCD) + bid / NXCD;  // bijective
    int tx   = swz % XT;
    int tmp  = swz / XT;
    int ty   = tmp % YT;
    int img  = tmp / YT;
    int x0   = tx * TDW;
    int y0   = ty * TDH;

    const float* ib = in + (size_t)img * IMG_STRIDE;

    // ---- 9 DMA instrs: instr i covers LDS rows 2i..2i+1 (64 chunks) ----
    // gx = x0 + 4*cin is ALWAYS in-image (no x-halo staged): only gy clamps,
    // and clamped rows land in dead LDS rows -> no fixups, no misplacement.
#pragma unroll
    for (int i = 0; i < NDMA; ++i) {
        int c   = i * 64 + lane;
        int row = c >> 5;                // 32 chunks per 128-float row
        int cin = c & 31;
        int gy  = y0 - 1 + row;
        gy = gy < 0 ? 0 : (gy > HH - 1 ? HH - 1 : gy);
        __builtin_amdgcn_global_load_lds(
            (const __attribute__((address_space(1))) void*)
                (ib + (size_t)gy * WW + x0 + 4 * cin),
            (__attribute__((address_space(3))) void*)(S + i * 256),
            16, 0, 0);
    }

    int f4c = lane & 31;                 // f4-column within tile
    int rh  = lane >> 5;                 // row half: rows rh*8 .. rh*8+7
    int Lb  = rh * 8;                    // first window LDS row for this lane
    const bool has_l = (x0 > 0);
    const bool has_r = (x0 + TDW < WW);
    const bool ldead = (f4c == 0  && !has_l);
    const bool rdead = (f4c == 31 && !has_r);

    // ---- tile-edge columns: 10 scalar loads on 2 lanes per side ----
    float el[10], er[10];
#pragma unroll
    for (int k = 0; k < 10; ++k) { el[k] = NEG; er[k] = NEG; }
    if (f4c == 0 && has_l) {
#pragma unroll
        for (int k = 0; k < 10; ++k) {
            int gy = y0 - 1 + Lb + k;
            gy = gy < 0 ? 0 : (gy > HH - 1 ? HH - 1 : gy);
            el[k] = ib[(size_t)gy * WW + x0 - 1];
        }
    }
    if (f4c == 31 && has_r) {
#pragma unroll
        for (int k = 0; k < 10; ++k) {
            int gy = y0 - 1 + Lb + k;
            gy = gy < 0 ? 0 : (gy > HH - 1 ? HH - 1 : gy);
            er[k] = ib[(size_t)gy * WW + x0 + TDW];
        }
    }

    // own-wave drain: orders all DMA (and edge loads) before the LDS reads;
    // "memory" clobber + sched_barrier keep ds_reads from hoisting (rule 18)
    asm volatile("s_waitcnt vmcnt(0)" ::: "memory");
    __builtin_amdgcn_sched_barrier(0);

    // ---- hmax of one LDS window row; k is always compile-time (unrolled) ----
    auto hrow = [&](int k, f4_t& val) -> f4_t {
        const float* p = S + (Lb + k) * TDW + f4c * 4;
        f4_t b = *(const f4_t*)p;        // aligned ds_read_b128, conflict-free
        float lw = __shfl_up(b.w, 1);    // left neighbor lane's last px
        float rx = __shfl_down(b.x, 1);  // right neighbor lane's first px
        float L = ldead ? NEG : (f4c == 0  ? el[k] : lw);
        float R = rdead ? NEG : (f4c == 31 ? er[k] : rx);
        val = b;
        f4_t h;
        h.x = max3f(L,   b.x, b.y);
        h.y = max3f(b.x, b.y, b.z);
        h.z = max3f(b.y, b.z, b.w);
        h.w = max3f(b.z, b.w, R);
        return h;
    };

    f4_t vd;
    f4_t hA = hrow(0, vd);               // LDS row Lb (gy = y0-1+Lb)
    if (rh == 0 && y0 == 0) hA = NEG4;   // image top: y0-1 doesn't exist
    f4_t vB;
    f4_t hB = hrow(1, vB);               // center row of first output

    float* ob = out + (size_t)img * IMG_STRIDE
                    + (size_t)(y0 + Lb) * WW + x0 + f4c * 4;
#pragma unroll
    for (int j = 0; j < 8; ++j) {
        f4_t vC;
        f4_t hC = hrow(j + 2, vC);
        if (j == 7 && rh == 1 && y0 + TDH == HH) hC = NEG4;  // image bottom
        f4_t o; float m, p;
        m = max3f(hA.x, hB.x, hC.x); p = fast_sigmoid(vB.x);
        o.x = (m == vB.x && p > 0.05f) ? p : 0.0f;
        m = max3f(hA.y, hB.y, hC.y); p = fast_sigmoid(vB.y);
        o.y = (m == vB.y && p > 0.05f) ? p : 0.0f;
        m = max3f(hA.z, hB.z, hC.z); p = fast_sigmoid(vB.z);
        o.z = (m == vB.z && p > 0.05f) ? p : 0.0f;
        m = max3f(hA.w, hB.w, hC.w); p = fast_sigmoid(vB.w);
        o.w = (m == vB.w && p > 0.05f) ? p : 0.0f;
        // output never re-read: keep L1/L2/L3 for the input stream
        __builtin_nontemporal_store(o, (f4_t*)(ob + (size_t)j * WW));
        hA = hB; hB = hC; vB = vC;
    }
}

extern "C" void kernel_launch(void* const* d_in, const int* in_sizes, int n_in,
                              void* d_out, int out_size, void* d_ws, size_t ws_size,
                              hipStream_t stream) {
    const float* in = (const float*)d_in[0];
    float* out = (float*)d_out;
    heatmap_peaks_wave<<<NBLOCKS, 64, 0, stream>>>(in, out);
}